// Round 1
// baseline (757.541 us; speedup 1.0000x reference)
//
#include <hip/hip_runtime.h>

#define CRF_B 256
#define CRF_S 1024
#define CRF_T 128
#define CH 2        // fwd: chains (batches) per block
#define GSPLIT 8    // gold: S-slices per batch (128 rows each)

typedef __attribute__((ext_vector_type(4))) float f32x4;

// Barrier that waits only on LDS ops (lgkmcnt), NOT vmcnt: keeps global
// em-prefetch loads in flight across steps (__syncthreads drains vmcnt(0)).
__device__ __forceinline__ void barrier_lds_only() {
    __asm__ volatile("s_waitcnt lgkmcnt(0)\n\ts_barrier" ::: "memory");
}

// Cross-lane butterfly adds on the VALU pipe (DPP), no LDS/bpermute.
__device__ __forceinline__ float dpp_add_xor1(float x) {      // quad_perm [1,0,3,2]
    int y = __builtin_amdgcn_mov_dpp(__float_as_int(x), 0xB1, 0xF, 0xF, false);
    return x + __int_as_float(y);
}
__device__ __forceinline__ float dpp_add_xor2(float x) {      // quad_perm [2,3,0,1]
    int y = __builtin_amdgcn_mov_dpp(__float_as_int(x), 0x4E, 0xF, 0xF, false);
    return x + __int_as_float(y);
}
// After xor1+xor2 the value is quad-uniform, so ROW_HALF_MIRROR (lane^7 within
// 8) acts as xor4: combines the two quads of each 8-lane row group.
__device__ __forceinline__ float dpp_add_xor4u(float x) {     // ROW_HALF_MIRROR
    int y = __builtin_amdgcn_mov_dpp(__float_as_int(x), 0x141, 0xF, 0xF, false);
    return x + __int_as_float(y);
}

__device__ __forceinline__ f32x4 exp4(f32x4 v) {
    f32x4 r;
    r.x = __expf(v.x); r.y = __expf(v.y); r.z = __expf(v.z); r.w = __expf(v.w);
    return r;
}
__device__ __forceinline__ float hsum4(f32x4 v) {
    return (v.x + v.y) + (v.z + v.w);
}

// ---------------------------------------------------------------------------
// Kernel 1: tag-gather terms (negated) + S2 = sum_t m_t*log(sum_j exp(em_tj)).
// S-split across GSPLIT blocks per batch: grid 2048 -> 8 blocks/CU, so the
// HBM-latency-bound reads are hidden by TLP (was 1 wave/SIMD -> ~6x too slow).
// ---------------------------------------------------------------------------
__global__ __launch_bounds__(256) void crf_gold_kernel(
    const float* __restrict__ em, const int* __restrict__ tags,
    const float* __restrict__ mask, const float* __restrict__ startT,
    const float* __restrict__ endT, const float* __restrict__ trans,
    float* __restrict__ out)
{
    const int b     = blockIdx.x >> 3;            // GSPLIT == 8
    const int slice = blockIdx.x & (GSPLIT - 1);
    const int base  = slice << 7;                 // 128 rows per slice
    const int tid = threadIdx.x;
    const int p = tid & 3;      // quad member
    const int q = tid >> 2;     // quad id 0..63
    const int* tg = tags + (size_t)b * CRF_S;
    const float* mk = mask + (size_t)b * CRF_S;
    const float* emr = em + (size_t)b * CRF_S * CRF_T;

    // ---- tag-gather part: one t per thread (tid<128) ----
    float g_acc = 0.f;
    if (tid < 128) {
        const int t = base + tid;
        const int tagt = tg[t];
        const float m = mk[t];
        g_acc += emr[(size_t)t * CRF_T + tagt] * m;
        if (t >= 1) g_acc += trans[tg[t - 1] * CRF_T + tagt] * m;
    }
    if (tid == 0 && slice == 0)
        g_acc += startT[tg[0]];
    if (tid == 0 && slice == GSPLIT - 1)
        g_acc += endT[tg[CRF_S - 1]] * mk[CRF_S - 1];

    // ---- S2 part: quad q handles rows base+q, base+q+64; lane p cols 4p+16k
    float s2 = 0.f;
#pragma unroll
    for (int it = 0; it < 2; ++it) {
        const int r = base + it * 64 + q;
        const float* row = emr + (size_t)r * CRF_T;
        f32x4 sum4 = {0.f, 0.f, 0.f, 0.f};
#pragma unroll
        for (int k = 0; k < 8; ++k)
            sum4 += exp4(*(const f32x4*)(row + k * 16 + p * 4));
        float s = hsum4(sum4);
        s = dpp_add_xor1(s);
        s = dpp_add_xor2(s);
        if (p == 0) s2 += __logf(s) * mk[r];
    }

    float contrib = s2 - g_acc;
#pragma unroll
    for (int d = 1; d < 64; d <<= 1) contrib += __shfl_xor(contrib, d);
    __shared__ float r4[4];
    if ((tid & 63) == 0) r4[tid >> 6] = contrib;
    __syncthreads();
    if (tid == 0) {
        float tot = (r4[0] + r4[1]) + (r4[2] + r4[3]);
        atomicAdd(out, tot * (1.0f / CRF_B));
    }
}

// ---------------------------------------------------------------------------
// Kernel 2: scaled linear-domain forward recursion, CH=2 chains per block.
// Waves 0-3 = chain 0, waves 4-7 = chain 1; HW round-robins waves to SIMDs so
// each SIMD carries one wave of EACH chain. The per-step fixed latency
// (ds_read ~120cy + barrier + reduce tails) is paid once per step while two
// chains' VALU issue interleaves in it -> stalls are filled with real work.
// Per chain unchanged: r = ct&7 row group, cq = ct>>3 col quad, E tile 16x4
// = 64 VGPRs/thread (no spill), swizzled ds_read_b128, DPP reduce, lgkm-only
// barrier, lazy rescale every 4 steps.
// ---------------------------------------------------------------------------
__global__ __launch_bounds__(256 * CH, 1) void crf_fwd_kernel(
    const float* __restrict__ em, const float* __restrict__ mask,
    const float* __restrict__ startT, const float* __restrict__ endT,
    const float* __restrict__ trans, float* __restrict__ out)
{
    const int tid = threadIdx.x;
    const int chain = tid >> 8;          // 0..CH-1 (wave-aligned: 4 waves each)
    const int ct = tid & 255;            // thread id within chain
    const int b = blockIdx.x * CH + chain;
    const int r = ct & 7;                // row group: rows r*16 .. r*16+15
    const int cq = ct >> 3;              // 0..31
    const int j0 = cq * 4;
    const bool leader = (r == 0);

    __shared__ __align__(16) float Abuf[CH][2][CRF_T];
    __shared__ __align__(16) float partsA[CH][32];
    __shared__ float red[CH][8];
    __shared__ float lzsh[CH];

    // k-swizzle: thread's 4 b128 reads at float-idx r*16 + ((k+r)&3)*4.
    int kidx[4];
#pragma unroll
    for (int k = 0; k < 4; ++k) kidx[k] = (k + r) & 3;

    // EE[k][c][s] = exp(trans[i][j0+c]), i = r*16 + kidx[k]*4 + s  (64 VGPRs)
    f32x4 EE[4][4];
#pragma unroll
    for (int k = 0; k < 4; ++k) {
#pragma unroll
        for (int s = 0; s < 4; ++s) {
            const int i = r * 16 + kidx[k] * 4 + s;
            f32x4 t4 = *(const f32x4*)&trans[i * CRF_T + j0];
            EE[k][0][s] = __expf(t4.x);
            EE[k][1][s] = __expf(t4.y);
            EE[k][2][s] = __expf(t4.z);
            EE[k][3][s] = __expf(t4.w);
        }
    }

    const float* emb = em + (size_t)b * CRF_S * CRF_T + j0;
    const float mlast = mask[(size_t)b * CRF_S + (CRF_S - 1)];

    float logZ = 0.f;   // leaders only
    float rc = 1.f;     // leaders only (non-leader alpha is never written)

    // em pipeline: eh[cur] in use, eh[nxt] built this group; emv = group g+2.
    f32x4 emv[4], eh[2][4];
#pragma unroll
    for (int k = 0; k < 4; ++k) emv[k] = *(const f32x4*)(emb + (size_t)k * CRF_T);
#pragma unroll
    for (int k = 0; k < 4; ++k) eh[0][k] = exp4(emv[k]);
#pragma unroll
    for (int k = 0; k < 4; ++k) emv[k] = *(const f32x4*)(emb + (size_t)(4 + k) * CRF_T);

    auto STEP = [&](int t, int role, f32x4 ehv) {
        const int rb = (t & 1) ^ 1, wb = t & 1;

        // t==1023's rescale is never applied -> must NOT enter logZ.
        if (role == 3 && leader && t < 1023) {
            const f32x4* pa = (const f32x4*)partsA[chain];   // csum from t-1
            f32x4 s8 = ((pa[0] + pa[1]) + (pa[2] + pa[3])) +
                       ((pa[4] + pa[5]) + (pa[6] + pa[7]));
            float c = hsum4(s8);
            rc = __builtin_amdgcn_rcpf(c);
            logZ += __logf(c);
        }

        const f32x4* Ab = (const f32x4*)&Abuf[chain][rb][r * 16];
        f32x4 ac0 = {0.f, 0.f, 0.f, 0.f}, ac1 = ac0, ac2 = ac0, ac3 = ac0;
#pragma unroll
        for (int k = 0; k < 4; ++k) {
            f32x4 av = Ab[kidx[k]];
            ac0 = __builtin_elementwise_fma(av, EE[k][0], ac0);
            ac1 = __builtin_elementwise_fma(av, EE[k][1], ac1);
            ac2 = __builtin_elementwise_fma(av, EE[k][2], ac2);
            ac3 = __builtin_elementwise_fma(av, EE[k][3], ac3);
        }
        float d0 = hsum4(ac0), d1 = hsum4(ac1), d2 = hsum4(ac2), d3 = hsum4(ac3);
        d0 = dpp_add_xor4u(dpp_add_xor2(dpp_add_xor1(d0)));
        d1 = dpp_add_xor4u(dpp_add_xor2(dpp_add_xor1(d1)));
        d2 = dpp_add_xor4u(dpp_add_xor2(dpp_add_xor1(d2)));
        d3 = dpp_add_xor4u(dpp_add_xor2(dpp_add_xor1(d3)));

        float a0 = d0 * ehv.x, a1 = d1 * ehv.y, a2 = d2 * ehv.z, a3 = d3 * ehv.w;
        if (role == 0) { a0 *= rc; a1 *= rc; a2 *= rc; a3 *= rc; }
        if (leader) {
            f32x4 av = {a0, a1, a2, a3};
            *(f32x4*)&Abuf[chain][wb][j0] = av;
            if (role == 2) partsA[chain][cq] = (a0 + a1) + (a2 + a3);
        }
        barrier_lds_only();
    };

    // ---- group 0: t=0 init + steps 1..3 ----
    {
        f32x4 s4 = *(const f32x4*)&startT[j0];
        if (leader) {
            f32x4 a;
            a.x = __expf(s4.x) * eh[0][0].x;
            a.y = __expf(s4.y) * eh[0][0].y;
            a.z = __expf(s4.z) * eh[0][0].z;
            a.w = __expf(s4.w) * eh[0][0].w;
            *(f32x4*)&Abuf[chain][0][j0] = a;
        }
        barrier_lds_only();
        STEP(1, 1, eh[0][1]);
#pragma unroll
        for (int k = 0; k < 4; ++k) eh[1][k] = exp4(emv[k]);   // group 1
        STEP(2, 2, eh[0][2]);
#pragma unroll
        for (int k = 0; k < 4; ++k) emv[k] = *(const f32x4*)(emb + (size_t)(8 + k) * CRF_T); // group 2
        STEP(3, 3, eh[0][3]);
    }

    // ---- groups 1..255 ----
#pragma unroll 1
    for (int g = 1; g < 256; ++g) {
        const int t0 = 4 * g;
        const int cur = g & 1, nxt = cur ^ 1;
        STEP(t0 + 0, 0, eh[cur][0]);
        STEP(t0 + 1, 1, eh[cur][1]);
        if (g <= 254) {
#pragma unroll
            for (int k = 0; k < 4; ++k) eh[nxt][k] = exp4(emv[k]);  // group g+1
        }
        STEP(t0 + 2, 2, eh[cur][2]);
        if (g <= 253) {
#pragma unroll
            for (int k = 0; k < 4; ++k)
                emv[k] = *(const f32x4*)(emb + (size_t)(t0 + 8 + k) * CRF_T); // group g+2
        }
        STEP(t0 + 3, 3, eh[cur][3]);
    }

    // ---- finale: A~_1023 in Abuf[chain][1]; logZ in leader lanes ----
    __syncthreads();
    if (ct == 0) lzsh[chain] = logZ;
    __syncthreads();
    const float lz = lzsh[chain];

    float v = -3.0e38f;
    if (ct < 128)
        v = (__logf(Abuf[chain][1][ct]) + lz) * mlast + endT[ct];
    float mx = v;
#pragma unroll
    for (int dd = 1; dd < 64; dd <<= 1) mx = fmaxf(mx, __shfl_xor(mx, dd));
    if ((ct & 63) == 0) red[chain][ct >> 6] = mx;
    __syncthreads();
    mx = fmaxf(fmaxf(red[chain][0], red[chain][1]),
               fmaxf(red[chain][2], red[chain][3]));
    float ex = (ct < 128) ? __expf(v - mx) : 0.f;
#pragma unroll
    for (int dd = 1; dd < 64; dd <<= 1) ex += __shfl_xor(ex, dd);
    if ((ct & 63) == 0) red[chain][4 + (ct >> 6)] = ex;
    __syncthreads();
    if (ct == 0) {
        float sm = (red[chain][4] + red[chain][5]) + (red[chain][6] + red[chain][7]);
        float fwd = mx + __logf(sm);
        atomicAdd(out, fwd * (1.0f / CRF_B));
    }
}

// ---------------------------------------------------------------------------
extern "C" void kernel_launch(void* const* d_in, const int* in_sizes, int n_in,
                              void* d_out, int out_size, void* d_ws, size_t ws_size,
                              hipStream_t stream)
{
    const float* em     = (const float*)d_in[0];
    const int*   tags   = (const int*)d_in[1];
    const float* mask   = (const float*)d_in[2];
    const float* startT = (const float*)d_in[3];
    const float* endT   = (const float*)d_in[4];
    const float* trans  = (const float*)d_in[5];
    float* out = (float*)d_out;

    hipMemsetAsync(out, 0, sizeof(float), stream);
    hipLaunchKernelGGL(crf_gold_kernel, dim3(CRF_B * GSPLIT), dim3(256), 0, stream,
                       em, tags, mask, startT, endT, trans, out);
    hipLaunchKernelGGL(crf_fwd_kernel, dim3(CRF_B / CH), dim3(256 * CH), 0, stream,
                       em, mask, startT, endT, trans, out);
}